// Round 1
// baseline (23.344 us; speedup 1.0000x reference)
//
#include <hip/hip_runtime.h>
#include <math.h>

#define BATCH 262144
#define NC 7

__global__ __launch_bounds__(256, 1)
void qcirc_kernel(const float* __restrict__ x_cont,
                  const float* __restrict__ x_cat,
                  const float* __restrict__ qw,
                  const float* __restrict__ head_w,
                  const float* __restrict__ head_b,
                  float* __restrict__ out)
{
    const int b = blockIdx.x * blockDim.x + threadIdx.x;

    // ---- load inputs (vectorized) ----
    const float4 c0 = *reinterpret_cast<const float4*>(x_cont + b * 8);
    const float4 c1 = *reinterpret_cast<const float4*>(x_cont + b * 8 + 4);
    const float4 xc = *reinterpret_cast<const float4*>(x_cat + b * 4);

    float a[8] = {c0.x, c0.y, c0.z, c0.w, c1.x, c1.y, c1.z, c1.w};
    float ss = 0.f;
#pragma unroll
    for (int i = 0; i < 8; ++i) ss += a[i] * a[i];
    const float inv = rsqrtf(ss);
#pragma unroll
    for (int i = 0; i < 8; ++i) a[i] *= inv;

    // angle-encoded qubits 3,4,5
    float s0, c_0, s1, c_1, s2, c_2;
    __sincosf(xc.x * 0.5f, &s0, &c_0);
    __sincosf(xc.y * 0.5f, &s1, &c_1);
    __sincosf(xc.z * 0.5f, &s2, &c_2);
    const float q3[2] = {c_0, s0};
    const float q4[2] = {c_1, s1};
    const float q5[2] = {c_2, s2};

    // ---- initial product state (real) ----
    // n = q0*32 + q1*16 + q2*8 + q3*4 + q4*2 + q5
    float sr[64], si[64];
#pragma unroll
    for (int n = 0; n < 64; ++n) {
        sr[n] = a[n >> 3] * q3[(n >> 2) & 1] * q4[(n >> 1) & 1] * q5[n & 1];
        si[n] = 0.f;   // compiler folds zeros through layer-1 gates
    }

    // ---- circuit: 2 layers of (6x RX, 6x ring-CNOT) ----
#pragma unroll
    for (int l = 0; l < 2; ++l) {
#pragma unroll
        for (int w = 0; w < 6; ++w) {
            const float th = qw[l * 6 + w] * 0.5f;  // wave-uniform (scalar load)
            float s, c;
            __sincosf(th, &s, &c);
            const int bit = 32 >> w;
#pragma unroll
            for (int n = 0; n < 64; ++n) {
                if (n & bit) continue;
                const int m = n | bit;
                const float ar = sr[n], ai = si[n];
                const float br = sr[m], bi = si[m];
                // U = [[c, -i s], [-i s, c]]
                sr[n] = c * ar + s * bi;
                si[n] = c * ai - s * br;
                sr[m] = c * br + s * ai;
                si[m] = c * bi - s * ar;
            }
        }
#pragma unroll
        for (int w = 0; w < 6; ++w) {
            const int cb = 32 >> w;
            const int tb = 32 >> ((w + 1) % 6);
#pragma unroll
            for (int n = 0; n < 64; ++n) {
                if ((n & cb) && !(n & tb)) {
                    const int m = n | tb;
                    float t;
                    t = sr[n]; sr[n] = sr[m]; sr[m] = t;
                    t = si[n]; si[n] = si[m]; si[m] = t;
                }
            }
        }
    }

    // ---- <Z0> expectation ----
    float z = 0.f;
#pragma unroll
    for (int n = 0; n < 64; ++n) {
        const float p = sr[n] * sr[n] + si[n] * si[n];
        z += (n < 32) ? p : -p;
    }

    // ---- linear head ----
#pragma unroll
    for (int c = 0; c < NC; ++c) {
        out[b * NC + c] = z * head_w[c] + head_b[c];
    }
}

extern "C" void kernel_launch(void* const* d_in, const int* in_sizes, int n_in,
                              void* d_out, int out_size, void* d_ws, size_t ws_size,
                              hipStream_t stream) {
    const float* x_cont = (const float*)d_in[0];
    const float* x_cat  = (const float*)d_in[1];
    const float* qw     = (const float*)d_in[2];
    const float* head_w = (const float*)d_in[3];
    const float* head_b = (const float*)d_in[4];
    float* out = (float*)d_out;

    const int threads = 256;
    const int blocks = BATCH / threads;  // 1024
    qcirc_kernel<<<blocks, threads, 0, stream>>>(x_cont, x_cat, qw, head_w, head_b, out);
}

// Round 2
// 16.388 us; speedup vs baseline: 1.4244x; 1.4244x over previous
//
#include <hip/hip_runtime.h>
#include <math.h>

#define BATCH 262144
#define NC 7

__global__ __launch_bounds__(256, 2)
void qcirc_kernel(const float* __restrict__ x_cont,
                  const float* __restrict__ x_cat,
                  const float* __restrict__ qw,
                  const float* __restrict__ head_w,
                  const float* __restrict__ head_b,
                  float* __restrict__ out)
{
    const int b = blockIdx.x * blockDim.x + threadIdx.x;

    // ---- load inputs (vectorized) ----
    const float4 c0 = *reinterpret_cast<const float4*>(x_cont + b * 8);
    const float4 c1 = *reinterpret_cast<const float4*>(x_cont + b * 8 + 4);
    const float4 xc = *reinterpret_cast<const float4*>(x_cat + b * 4);

    float a[8] = {c0.x, c0.y, c0.z, c0.w, c1.x, c1.y, c1.z, c1.w};
    float ss = 0.f;
#pragma unroll
    for (int i = 0; i < 8; ++i) ss += a[i] * a[i];
    const float inv = rsqrtf(ss);
#pragma unroll
    for (int i = 0; i < 8; ++i) a[i] *= inv;

    // ---- layer-1 gate angles (wave-uniform) ----
    float c1w[6], s1w[6];
#pragma unroll
    for (int w = 0; w < 6; ++w) {
        const float th = qw[w] * 0.5f;
        c1w[w] = __cosf(th);
        s1w[w] = __sinf(th);
    }

    // ---- layer-1 RX on qubits 0..2, applied to the 8-dim amp block ----
    // i bit2 = qubit0, bit1 = qubit1, bit0 = qubit2
    float Ar[8], Ai[8];
    {
        const float c = c1w[0], s = s1w[0];
#pragma unroll
        for (int i = 0; i < 4; ++i) {            // pairs (i, i|4), real input
            Ar[i]     = c * a[i];     Ai[i]     = -s * a[i + 4];
            Ar[i + 4] = c * a[i + 4]; Ai[i + 4] = -s * a[i];
        }
    }
#pragma unroll
    for (int g = 1; g < 3; ++g) {                // qubit1 (bit 2->?), qubit2
        const float c = c1w[g], s = s1w[g];
        const int bit = 4 >> g;                  // g=1 -> 2, g=2 -> 1
#pragma unroll
        for (int n = 0; n < 8; ++n) {
            if (n & bit) continue;
            const int m = n | bit;
            const float ar = Ar[n], ai = Ai[n];
            const float br = Ar[m], bi = Ai[m];
            Ar[n] = c * ar + s * bi;
            Ai[n] = c * ai - s * br;
            Ar[m] = c * br + s * ai;
            Ai[m] = c * bi - s * ar;
        }
    }

    // ---- layer-1 RX on qubits 3..5, applied to the 2-dim factors ----
    float h3c, h3s, h4c, h4s, h5c, h5s;
    h3c = __cosf(xc.x * 0.5f); h3s = __sinf(xc.x * 0.5f);
    h4c = __cosf(xc.y * 0.5f); h4s = __sinf(xc.y * 0.5f);
    h5c = __cosf(xc.z * 0.5f); h5s = __sinf(xc.z * 0.5f);

    float g3r[2], g3i[2], g4r[2], g4i[2], g5r[2], g5i[2];
    {
        const float c = c1w[3], s = s1w[3];
        g3r[0] = c * h3c; g3i[0] = -s * h3s;
        g3r[1] = c * h3s; g3i[1] = -s * h3c;
    }
    {
        const float c = c1w[4], s = s1w[4];
        g4r[0] = c * h4c; g4i[0] = -s * h4s;
        g4r[1] = c * h4s; g4i[1] = -s * h4c;
    }
    {
        const float c = c1w[5], s = s1w[5];
        g5r[0] = c * h5c; g5i[0] = -s * h5s;
        g5r[1] = c * h5s; g5i[1] = -s * h5c;
    }

    // Q = g3 (x) g4 (x) g5 : j bit2=q3, bit1=q4, bit0=q5
    float Tr[4], Ti[4];
#pragma unroll
    for (int p = 0; p < 2; ++p)
#pragma unroll
        for (int q = 0; q < 2; ++q) {
            Tr[p * 2 + q] = g3r[p] * g4r[q] - g3i[p] * g4i[q];
            Ti[p * 2 + q] = g3r[p] * g4i[q] + g3i[p] * g4r[q];
        }
    float Qr[8], Qi[8];
#pragma unroll
    for (int t = 0; t < 4; ++t)
#pragma unroll
        for (int u = 0; u < 2; ++u) {
            Qr[t * 2 + u] = Tr[t] * g5r[u] - Ti[t] * g5i[u];
            Qi[t * 2 + u] = Tr[t] * g5i[u] + Ti[t] * g5r[u];
        }

    // ---- full post-layer-1-RX state: psi[n] = A[i] * Q[j], n = i*8 + j ----
    float sr[64], si[64];
#pragma unroll
    for (int i = 0; i < 8; ++i)
#pragma unroll
        for (int j = 0; j < 8; ++j) {
            sr[i * 8 + j] = Ar[i] * Qr[j] - Ai[i] * Qi[j];
            si[i * 8 + j] = Ar[i] * Qi[j] + Ai[i] * Qr[j];
        }

    // ---- layer-1 CNOT ring: pure index permutation (register renames) ----
#pragma unroll
    for (int w = 0; w < 6; ++w) {
        const int cb = 32 >> w;
        const int tb = 32 >> ((w + 1) % 6);
#pragma unroll
        for (int n = 0; n < 64; ++n) {
            if ((n & cb) && !(n & tb)) {
                const int m = n | tb;
                float t;
                t = sr[n]; sr[n] = sr[m]; sr[m] = t;
                t = si[n]; si[n] = si[m]; si[m] = t;
            }
        }
    }

    // ---- layer-2 RX on qubits 1..5 only ----
    // (RX on qubit 0 commutes with the effective observable Z1..Z5 -> skipped;
    //  layer-2 CNOT ring conjugates Z0 to Z1Z2Z3Z4Z5 -> absorbed into measurement)
#pragma unroll
    for (int w = 1; w < 6; ++w) {
        const float th = qw[6 + w] * 0.5f;
        const float c = __cosf(th);
        const float s = __sinf(th);
        const int bit = 32 >> w;
#pragma unroll
        for (int n = 0; n < 64; ++n) {
            if (n & bit) continue;
            const int m = n | bit;
            const float ar = sr[n], ai = si[n];
            const float br = sr[m], bi = si[m];
            sr[n] = c * ar + s * bi;
            si[n] = c * ai - s * br;
            sr[m] = c * br + s * ai;
            si[m] = c * bi - s * ar;
        }
    }

    // ---- <Z1 Z2 Z3 Z4 Z5> : parity of bits 4..0 ----
    float zp = 0.f, zm = 0.f;
#pragma unroll
    for (int n = 0; n < 64; ++n) {
        const float p = sr[n] * sr[n] + si[n] * si[n];
        if (__builtin_popcount(n & 31) & 1) zm += p; else zp += p;
    }
    const float z = zp - zm;

    // ---- linear head ----
#pragma unroll
    for (int c = 0; c < NC; ++c) {
        out[b * NC + c] = z * head_w[c] + head_b[c];
    }
}

extern "C" void kernel_launch(void* const* d_in, const int* in_sizes, int n_in,
                              void* d_out, int out_size, void* d_ws, size_t ws_size,
                              hipStream_t stream) {
    (void)in_sizes; (void)n_in; (void)out_size; (void)d_ws; (void)ws_size;
    const float* x_cont = (const float*)d_in[0];
    const float* x_cat  = (const float*)d_in[1];
    const float* qw     = (const float*)d_in[2];
    const float* head_w = (const float*)d_in[3];
    const float* head_b = (const float*)d_in[4];
    float* out = (float*)d_out;

    const int threads = 256;
    const int blocks = BATCH / threads;  // 1024
    qcirc_kernel<<<blocks, threads, 0, stream>>>(x_cont, x_cat, qw, head_w, head_b, out);
}

// Round 3
// 11.343 us; speedup vs baseline: 2.0579x; 1.4447x over previous
//
#include <hip/hip_runtime.h>
#include <math.h>

#define BATCH 262144
#define NC 7

__device__ __forceinline__ float cre(float xr, float xi, float yr, float yi) {
    return xr * yr + xi * yi;   // Re(conj(x) * y)
}
__device__ __forceinline__ float cim(float xr, float xi, float yr, float yi) {
    return xr * yi - xi * yr;   // Im(conj(x) * y)
}

__global__ __launch_bounds__(256, 4)
void qcirc_kernel(const float* __restrict__ x_cont,
                  const float* __restrict__ x_cat,
                  const float* __restrict__ qw,
                  const float* __restrict__ head_w,
                  const float* __restrict__ head_b,
                  float* __restrict__ out)
{
    const int b = blockIdx.x * blockDim.x + threadIdx.x;

    // ---- loads ----
    const float4 c0 = *reinterpret_cast<const float4*>(x_cont + b * 8);
    const float4 c1 = *reinterpret_cast<const float4*>(x_cont + b * 8 + 4);
    const float4 xc = *reinterpret_cast<const float4*>(x_cat + b * 4);

    float a[8] = {c0.x, c0.y, c0.z, c0.w, c1.x, c1.y, c1.z, c1.w};
    float ss = 0.f;
#pragma unroll
    for (int i = 0; i < 8; ++i) ss += a[i] * a[i];
    const float inv = rsqrtf(ss);
#pragma unroll
    for (int i = 0; i < 8; ++i) a[i] *= inv;

    // ---- wave-uniform trig: layer-1 half-angles, layer-2 full angles ----
    float c1w[6], s1w[6];
#pragma unroll
    for (int w = 0; w < 6; ++w) {
        const float th = qw[w] * 0.5f;
        c1w[w] = __cosf(th);
        s1w[w] = __sinf(th);
    }
    // layer-2 kappa: RX(th)^dag Z RX(th) = cos(th) Z + sin(th) Y   (FULL angle)
    float ck[6], sk[6];
#pragma unroll
    for (int w = 1; w < 6; ++w) {
        const float th = qw[6 + w];
        ck[w] = __cosf(th);
        sk[w] = __sinf(th);
    }

    // ---- layer-1 RX on qubits 0..2, applied to the 8-dim amp block ----
    float Ar[8], Ai[8];
    {
        const float c = c1w[0], s = s1w[0];
#pragma unroll
        for (int i = 0; i < 4; ++i) {            // real input: half the work
            Ar[i]     = c * a[i];     Ai[i]     = -s * a[i + 4];
            Ar[i + 4] = c * a[i + 4]; Ai[i + 4] = -s * a[i];
        }
    }
#pragma unroll
    for (int g = 1; g < 3; ++g) {
        const float c = c1w[g], s = s1w[g];
        const int bit = 4 >> g;
#pragma unroll
        for (int n = 0; n < 8; ++n) {
            if (n & bit) continue;
            const int m = n | bit;
            const float ar = Ar[n], ai = Ai[n];
            const float br = Ar[m], bi = Ai[m];
            Ar[n] = c * ar + s * bi;
            Ai[n] = c * ai - s * br;
            Ar[m] = c * br + s * ai;
            Ai[m] = c * bi - s * ar;
        }
    }

    // ---- layer-1 RX on qubits 3..5 -> single-qubit states g3,g4,g5 ----
    float h3c = __cosf(xc.x * 0.5f), h3s = __sinf(xc.x * 0.5f);
    float h4c = __cosf(xc.y * 0.5f), h4s = __sinf(xc.y * 0.5f);
    float h5c = __cosf(xc.z * 0.5f), h5s = __sinf(xc.z * 0.5f);

    float g3r0, g3i0, g3r1, g3i1, g4r0, g4i0, g4r1, g4i1, g5r0, g5i0, g5r1, g5i1;
    { const float c = c1w[3], s = s1w[3];
      g3r0 = c * h3c; g3i0 = -s * h3s; g3r1 = c * h3s; g3i1 = -s * h3c; }
    { const float c = c1w[4], s = s1w[4];
      g4r0 = c * h4c; g4i0 = -s * h4s; g4r1 = c * h4s; g4i1 = -s * h4c; }
    { const float c = c1w[5], s = s1w[5];
      g5r0 = c * h5c; g5i0 = -s * h5s; g5r1 = c * h5s; g5i1 = -s * h5c; }

    // ---- single-qubit expectations on g3,g4,g5 ----
    const float e3Z = (g3r0 * g3r0 + g3i0 * g3i0) - (g3r1 * g3r1 + g3i1 * g3i1);
    const float e3Y = 2.f * (g3r0 * g3i1 - g3i0 * g3r1);
    const float e4X = 2.f * (g4r0 * g4r1 + g4i0 * g4i1);
    const float e5Z = (g5r0 * g5r0 + g5i0 * g5i0) - (g5r1 * g5r1 + g5i1 * g5i1);
    const float e5Y = 2.f * (g5r0 * g5i1 - g5i0 * g5r1);

    // ---- 3-qubit expectations F[L0][L1][L2] on A ----
    // Gram matrices over u=(q0,q1)-pairs: M^I_{u,v} = sum_c conj(A_{u,c}) A_{v,c}
    //                                     M^X_{u,v} = sum_c conj(A_{u,c}) A_{v,1-c}
    // A index: i = 4*q0 + 2*q1 + q2 = 2u + c.
    float DI[4], DX[4];
#pragma unroll
    for (int u = 0; u < 4; ++u) {
        const float xr0 = Ar[2 * u], xi0 = Ai[2 * u];
        const float xr1 = Ar[2 * u + 1], xi1 = Ai[2 * u + 1];
        DI[u] = xr0 * xr0 + xi0 * xi0 + xr1 * xr1 + xi1 * xi1;
        DX[u] = 2.f * (xr0 * xr1 + xi0 * xi1);
    }
#define IM_I(u, v) (cim(Ar[2*(u)], Ai[2*(u)], Ar[2*(v)], Ai[2*(v)]) + \
                    cim(Ar[2*(u)+1], Ai[2*(u)+1], Ar[2*(v)+1], Ai[2*(v)+1]))
#define RE_I(u, v) (cre(Ar[2*(u)], Ai[2*(u)], Ar[2*(v)], Ai[2*(v)]) + \
                    cre(Ar[2*(u)+1], Ai[2*(u)+1], Ar[2*(v)+1], Ai[2*(v)+1]))
#define IM_X(u, v) (cim(Ar[2*(u)], Ai[2*(u)], Ar[2*(v)+1], Ai[2*(v)+1]) + \
                    cim(Ar[2*(u)+1], Ai[2*(u)+1], Ar[2*(v)], Ai[2*(v)]))
#define RE_X(u, v) (cre(Ar[2*(u)], Ai[2*(u)], Ar[2*(v)+1], Ai[2*(v)+1]) + \
                    cre(Ar[2*(u)+1], Ai[2*(u)+1], Ar[2*(v)], Ai[2*(v)]))

    float F[2][2][2];
    F[0][0][0] = DI[0] - DI[1] - DI[2] + DI[3];          // <Z Z I>
    F[0][0][1] = DX[0] - DX[1] - DX[2] + DX[3];          // <Z Z X>
    F[0][1][0] = 2.f * (IM_I(0, 1) - IM_I(2, 3));        // <Z Y I>
    F[0][1][1] = 2.f * (IM_X(0, 1) - IM_X(2, 3));        // <Z Y X>
    F[1][0][0] = 2.f * (IM_I(0, 2) - IM_I(1, 3));        // <Y Z I>
    F[1][0][1] = 2.f * (IM_X(0, 2) - IM_X(1, 3));        // <Y Z X>
    F[1][1][0] = 2.f * (RE_I(1, 2) - RE_I(0, 3));        // <Y Y I>
    F[1][1][1] = 2.f * (RE_X(1, 2) - RE_X(0, 3));        // <Y Y X>
#undef IM_I
#undef RE_I
#undef IM_X
#undef RE_X

    // ---- factored Pauli sum ----
    // letters: L0=Z/Y by y5; L1 by y1^y5; L2=I/X by y1^y2; L3 by y2^y3;
    //          L4=I/X by y3^y4; L5 by y4^y5.
    // sign = (-1)^(y5 + y1*y5 + y2*y3 + y4*y5)
    const float E3[2] = {e3Z, e3Y};
    const float E5[2] = {e5Z, e5Y};

    float W[2][2];                // W[y2][y5] = inner sum over y3,y4
#pragma unroll
    for (int y2 = 0; y2 < 2; ++y2)
#pragma unroll
        for (int y5 = 0; y5 < 2; ++y5) {
            float acc = 0.f;
#pragma unroll
            for (int y3 = 0; y3 < 2; ++y3)
#pragma unroll
                for (int y4 = 0; y4 < 2; ++y4) {
                    float t = (y3 ? sk[3] : ck[3]) * (y4 ? sk[4] : ck[4]);
                    t *= E3[y2 ^ y3] * E5[y4 ^ y5];
                    if (y3 ^ y4) t *= e4X;
                    if ((y2 & y3) ^ (y4 & y5)) t = -t;
                    acc += t;
                }
            W[y2][y5] = acc;
        }

    float z = 0.f;
#pragma unroll
    for (int y5 = 0; y5 < 2; ++y5)
#pragma unroll
        for (int y1 = 0; y1 < 2; ++y1)
#pragma unroll
            for (int y2 = 0; y2 < 2; ++y2) {
                float t = (y1 ? sk[1] : ck[1]) * (y2 ? sk[2] : ck[2]) *
                          (y5 ? sk[5] : ck[5]);
                t *= F[y5][y1 ^ y5][y1 ^ y2] * W[y2][y5];
                if (y5 && !y1) t = -t;   // (-1)^(y5 + y1*y5)
                z += t;
            }

    // ---- linear head ----
#pragma unroll
    for (int c = 0; c < NC; ++c) {
        out[b * NC + c] = z * head_w[c] + head_b[c];
    }
}

extern "C" void kernel_launch(void* const* d_in, const int* in_sizes, int n_in,
                              void* d_out, int out_size, void* d_ws, size_t ws_size,
                              hipStream_t stream) {
    (void)in_sizes; (void)n_in; (void)out_size; (void)d_ws; (void)ws_size;
    const float* x_cont = (const float*)d_in[0];
    const float* x_cat  = (const float*)d_in[1];
    const float* qw     = (const float*)d_in[2];
    const float* head_w = (const float*)d_in[3];
    const float* head_b = (const float*)d_in[4];
    float* out = (float*)d_out;

    const int threads = 256;
    const int blocks = BATCH / threads;  // 1024
    qcirc_kernel<<<blocks, threads, 0, stream>>>(x_cont, x_cat, qw, head_w, head_b, out);
}